// Round 12
// baseline (125.241 us; speedup 1.0000x reference)
//
#include <hip/hip_runtime.h>
#include <hip/hip_bf16.h>

// Problem constants (fixed by the reference)
#define I_CAPS 128
#define N_CAPS 5
#define D_CAPS 153
#define D_PAD  160      // padded capsule dim (16B-aligned c-blocks, zeros in 153..159)
#define MLD    800      // hat_m leading dim = 5 * 160
#define IN_DIM 768
#define NQ     256
#define CD     765      // N_CAPS * D_CAPS
#define NPAIR  640      // I_CAPS * N_CAPS
#define EPSF   1e-8f
#define KHALF  384      // IN_DIM / 2 (split-K)

typedef __hip_bfloat16 bf16;

__device__ __forceinline__ float wred(float x) {
#pragma unroll
  for (int off = 32; off; off >>= 1) x += __shfl_down(x, off, 64);
  return x;
}

__device__ __forceinline__ float tanh_fast(float x) {
  float t = __expf(-2.f * fabsf(x));
  float r = (1.f - t) / (1.f + t);
  return copysignf(r, x);
}

__device__ __forceinline__ float squash_sc(float n2) {
  return (n2 / (1.f + n2)) * rsqrtf(n2 + EPSF);
}

// ---------------------------------------------------------------------------
// Kernel 0: input-dtype classifier. flag=1 -> bf16 inputs, flag=0 -> f32.
// ---------------------------------------------------------------------------
__global__ void classify_kernel(const unsigned* __restrict__ m_u32,
                                int* __restrict__ flag) {
  int lane = threadIdx.x & 63;
  unsigned u = m_u32[lane];
  int e = (u >> 7) & 0xFF;
  int hit = (e >= 118 && e <= 134) ? 1 : 0;
  unsigned long long mask = __ballot(hit);
  if (lane == 0) *flag = (__popcll(mask) >= 48) ? 1 : 0;
}

// ---------------------------------------------------------------------------
// Kernel 1: GEMM — split-K x2, 16-row x 64-col tiles (4 rows/thread -> W's
// L2 traffic halved vs 8-row, FMA:load 4:1), atomicAdd combine.
// grid (12, 24, 2), block (64, 4). hat buffers pre-zeroed; kb==0 adds bias.
// ---------------------------------------------------------------------------
template <bool ISB>
__device__ __forceinline__ float ld_in(const void* p, long idx) {
  if (ISB) return __bfloat162float(((const bf16*)p)[idx]);
  return ((const float*)p)[idx];
}

template <bool ISB>
__device__ void gemm_body(const void* m, const void* q, const void* W,
                          const void* b, float* hat_m, float* hat_q) {
  __shared__ float As[16][KHALF];   // 24 KB
  const int tx = threadIdx.x, ty = threadIdx.y;
  const int t = ty * 64 + tx;       // 0..255
  const int row0 = blockIdx.y * 16;
  const int k0 = blockIdx.z * KHALF;

  if (ISB) {
    for (int e = t; e < 16 * KHALF; e += 256) {
      int rr = e / KHALF, kk = e - rr * KHALF;
      int row = row0 + rr;
      As[rr][kk] = (row < I_CAPS)
                       ? ld_in<true>(m, (long)row * IN_DIM + k0 + kk)
                       : ld_in<true>(q, (long)(row - I_CAPS) * IN_DIM + k0 + kk);
    }
  } else {
    for (int e = t; e < 16 * (KHALF / 4); e += 256) {
      int rr = e / (KHALF / 4), k4 = e - rr * (KHALF / 4);
      int row = row0 + rr;
      const float* src = (row < I_CAPS)
                             ? (const float*)m + (long)row * IN_DIM
                             : (const float*)q + (long)(row - I_CAPS) * IN_DIM;
      *(float4*)&As[rr][k4 * 4] = *(const float4*)(src + k0 + k4 * 4);
    }
  }
  __syncthreads();

  const int col = blockIdx.x * 64 + tx;
  const int colc = (col < CD) ? col : (CD - 1);
  const int r0 = ty * 4;

  float acc[4][2];
#pragma unroll
  for (int r = 0; r < 4; ++r) { acc[r][0] = 0.f; acc[r][1] = 0.f; }

#pragma unroll 2
  for (int k = 0; k < KHALF; k += 8) {
    float w0 = ld_in<ISB>(W, (long)(k0 + k + 0) * CD + colc);
    float w1 = ld_in<ISB>(W, (long)(k0 + k + 1) * CD + colc);
    float w2 = ld_in<ISB>(W, (long)(k0 + k + 2) * CD + colc);
    float w3 = ld_in<ISB>(W, (long)(k0 + k + 3) * CD + colc);
    float w4 = ld_in<ISB>(W, (long)(k0 + k + 4) * CD + colc);
    float w5 = ld_in<ISB>(W, (long)(k0 + k + 5) * CD + colc);
    float w6 = ld_in<ISB>(W, (long)(k0 + k + 6) * CD + colc);
    float w7 = ld_in<ISB>(W, (long)(k0 + k + 7) * CD + colc);
#pragma unroll
    for (int r = 0; r < 4; ++r) {
      const float4 Aa = *(const float4*)&As[r0 + r][k];
      const float4 Ab = *(const float4*)&As[r0 + r][k + 4];
      acc[r][0] = fmaf(Aa.x, w0, acc[r][0]);
      acc[r][1] = fmaf(Aa.y, w1, acc[r][1]);
      acc[r][0] = fmaf(Aa.z, w2, acc[r][0]);
      acc[r][1] = fmaf(Aa.w, w3, acc[r][1]);
      acc[r][0] = fmaf(Ab.x, w4, acc[r][0]);
      acc[r][1] = fmaf(Ab.y, w5, acc[r][1]);
      acc[r][0] = fmaf(Ab.z, w6, acc[r][0]);
      acc[r][1] = fmaf(Ab.w, w7, acc[r][1]);
    }
  }

  if (col < CD) {
    float bias = (blockIdx.z == 0) ? ld_in<ISB>(b, col) : 0.f;
    int c = col / D_CAPS, d = col - c * D_CAPS;
#pragma unroll
    for (int r = 0; r < 4; ++r) {
      int row = row0 + r0 + r;
      float p = acc[r][0] + acc[r][1] + bias;
      float* dst = (row < I_CAPS) ? &hat_m[row * MLD + c * D_PAD + d]
                                  : &hat_q[(row - I_CAPS) * CD + col];
      atomicAdd(dst, p);
    }
  }
}

__global__ __launch_bounds__(256, 4)
void gemm_kernel(const void* m, const void* q, const void* W, const void* b,
                 const int* __restrict__ flag,
                 float* __restrict__ hat_m, float* __restrict__ hat_q) {
  if (*flag)
    gemm_body<true>(m, q, W, b, hat_m, hat_q);
  else
    gemm_body<false>(m, q, W, b, hat_m, hat_q);
}

// ---------------------------------------------------------------------------
// Kernel 2: per-(i,c) stats of hat_m — one wave per pair. grid 160, block 256.
// ---------------------------------------------------------------------------
__global__ __launch_bounds__(256)
void stats_kernel(const float* __restrict__ hat_m,
                  float* __restrict__ mean_m, float* __restrict__ ssm) {
  const int wave = threadIdx.x >> 6, lane = threadIdx.x & 63;
  const int pair = blockIdx.x * 4 + wave;
  const int i = pair / N_CAPS, c = pair - i * N_CAPS;
  const float* hm = hat_m + i * MLD + c * D_PAD;
  float s = 0.f, s2 = 0.f;
  for (int d = lane; d < D_CAPS; d += 64) {
    float x = hm[d];
    s += x;
    s2 = fmaf(x, x, s2);
  }
  s = wred(s);
  s2 = wred(s2);
  if (lane == 0) {
    float mu = s * (1.f / D_CAPS);
    mean_m[pair] = mu;
    ssm[pair] = fmaxf(s2 - (float)D_CAPS * mu * mu, 0.f);
  }
}

// ---------------------------------------------------------------------------
// Kernel 2b: Gram matrix G[c][j][i] = hm_i,c . hm_j,c. grid (5, 128), blk 128.
// ---------------------------------------------------------------------------
__global__ __launch_bounds__(128)
void gram_kernel(const float* __restrict__ hat_m, float* __restrict__ G) {
  const int c = blockIdx.x, j = blockIdx.y, i = threadIdx.x;
  const float4* hi = (const float4*)(hat_m + i * MLD + c * D_PAD);
  const float4* hj = (const float4*)(hat_m + j * MLD + c * D_PAD);
  float a0 = 0.f, a1 = 0.f, a2 = 0.f, a3 = 0.f;
#pragma unroll 8
  for (int k = 0; k < 40; ++k) {
    float4 x = hi[k];
    float4 y = hj[k];
    a0 = fmaf(x.x, y.x, a0);
    a1 = fmaf(x.y, y.y, a1);
    a2 = fmaf(x.z, y.z, a2);
    a3 = fmaf(x.w, y.w, a3);
  }
  G[c * 16384 + j * 128 + i] = (a0 + a1) + (a2 + a3);
}

// ---------------------------------------------------------------------------
// Kernel 3: routing — one block per query, 1024 threads. Gram-assisted.
// 3 barriers/round (scalar phase merged into pair-update via redundant
// per-thread scalar compute; Tsum/T2 double-buffered by round parity).
// No hat_v: final dsp written transposed (dspT[c][q][i]) + squash scale
// scT[c][q] from n2 = dsp^T G dsp; outgemm_kernel builds the output.
// ---------------------------------------------------------------------------
__global__ __launch_bounds__(1024, 4)
void routing_kernel(const float* __restrict__ hat_m,
                    const float* __restrict__ hat_q,
                    const float* __restrict__ Gmat,
                    const float* __restrict__ mean_m,
                    const float* __restrict__ ssm,
                    float* __restrict__ dspT,
                    float* __restrict__ scT) {
  __shared__ float tq[N_CAPS * D_PAD];
  __shared__ float aa[NPAIR], pp[NPAIR], dsp[NPAIR], sdot[NPAIR];
  __shared__ float smm[NPAIR], sss[NPAIR];
  __shared__ float meanq0[N_CAPS], ssq0[N_CAPS];
  __shared__ float tsum_s[2][N_CAPS], t2_s[2][N_CAPS];
  __shared__ float red[10][4];

  const int tid = threadIdx.x;
  const int qi = blockIdx.x;
  const int w = tid >> 6, lane = tid & 63;
  const int g = tid >> 3, sub = tid & 7;   // 128 groups of 8 lanes; i = g
  const float* hq = hat_q + qi * CD;
  const float* hm = hat_m + g * MLD;

  for (int l = tid; l < N_CAPS * D_PAD; l += 1024) {
    int c = l / D_PAD, d = l - c * D_PAD;
    tq[l] = (d < D_CAPS) ? hq[c * D_CAPS + d] : 0.f;
  }
  if (tid < NPAIR) {
    aa[tid] = 0.f;
    smm[tid] = mean_m[tid];
    sss[tid] = ssm[tid];
  }
  __syncthreads();

  // initial per-c stats of tq (raw Tsum/T2 saved for the recurrence)
  if (w < N_CAPS) {
    const int c = w;
    float s = 0.f, s2 = 0.f;
    for (int d = lane; d < D_CAPS; d += 64) {
      float x = tq[c * D_PAD + d];
      s += x;
      s2 = fmaf(x, x, s2);
    }
    s = wred(s);
    s2 = wred(s2);
    if (lane == 0) {
      float mu = s * (1.f / D_CAPS);
      tsum_s[0][c] = s;
      t2_s[0][c] = s2;
      meanq0[c] = mu;
      ssq0[c] = fmaxf(s2 - (float)D_CAPS * mu * mu, 0.f);
    }
  }
  __syncthreads();

  // init S = hm.tq (8-lane group per i, 5 c-chains, float4)
  {
    float A0 = 0.f, A1 = 0.f, A2 = 0.f, A3 = 0.f, A4 = 0.f;
#pragma unroll 2
    for (int jj = 0; jj < 5; ++jj) {
      int d = jj * 32 + sub * 4;
      float4 h0 = *(const float4*)(hm + 0 * D_PAD + d);
      float4 h1 = *(const float4*)(hm + 1 * D_PAD + d);
      float4 h2 = *(const float4*)(hm + 2 * D_PAD + d);
      float4 h3 = *(const float4*)(hm + 3 * D_PAD + d);
      float4 h4 = *(const float4*)(hm + 4 * D_PAD + d);
      float4 t0 = *(const float4*)(tq + 0 * D_PAD + d);
      float4 t1 = *(const float4*)(tq + 1 * D_PAD + d);
      float4 t2 = *(const float4*)(tq + 2 * D_PAD + d);
      float4 t3 = *(const float4*)(tq + 3 * D_PAD + d);
      float4 t4 = *(const float4*)(tq + 4 * D_PAD + d);
      A0 = fmaf(h0.x, t0.x, A0); A0 = fmaf(h0.y, t0.y, A0);
      A0 = fmaf(h0.z, t0.z, A0); A0 = fmaf(h0.w, t0.w, A0);
      A1 = fmaf(h1.x, t1.x, A1); A1 = fmaf(h1.y, t1.y, A1);
      A1 = fmaf(h1.z, t1.z, A1); A1 = fmaf(h1.w, t1.w, A1);
      A2 = fmaf(h2.x, t2.x, A2); A2 = fmaf(h2.y, t2.y, A2);
      A2 = fmaf(h2.z, t2.z, A2); A2 = fmaf(h2.w, t2.w, A2);
      A3 = fmaf(h3.x, t3.x, A3); A3 = fmaf(h3.y, t3.y, A3);
      A3 = fmaf(h3.z, t3.z, A3); A3 = fmaf(h3.w, t3.w, A3);
      A4 = fmaf(h4.x, t4.x, A4); A4 = fmaf(h4.y, t4.y, A4);
      A4 = fmaf(h4.z, t4.z, A4); A4 = fmaf(h4.w, t4.w, A4);
    }
#pragma unroll
    for (int off = 1; off < 8; off <<= 1) {
      A0 += __shfl_xor(A0, off, 64);
      A1 += __shfl_xor(A1, off, 64);
      A2 += __shfl_xor(A2, off, 64);
      A3 += __shfl_xor(A3, off, 64);
      A4 += __shfl_xor(A4, off, 64);
    }
    if (sub < N_CAPS) {
      float acc = A0;
      acc = (sub == 1) ? A1 : acc;
      acc = (sub == 2) ? A2 : acc;
      acc = (sub == 3) ? A3 : acc;
      acc = (sub == 4) ? A4 : acc;
      int ic = g * N_CAPS + sub;
      sdot[ic] = acc;
      float num = acc - (float)D_CAPS * smm[ic] * meanq0[sub];
      float den = sqrtf(sss[ic]) * sqrtf(ssq0[sub]) + EPSF;
      pp[ic] = tanh_fast(num / den);
    }
  }
  __syncthreads();

  auto softmax_dsp = [&]() {
    if (tid < I_CAPS) {
      float av[N_CAPS], ev[N_CAPS];
      float mx = -1e30f;
#pragma unroll
      for (int c = 0; c < N_CAPS; ++c) {
        av[c] = aa[tid * N_CAPS + c];
        mx = fmaxf(mx, av[c]);
      }
      float s = 0.f;
#pragma unroll
      for (int c = 0; c < N_CAPS; ++c) {
        ev[c] = __expf(av[c] - mx);
        s += ev[c];
      }
      float inv = 1.f / s;
#pragma unroll
      for (int c = 0; c < N_CAPS; ++c)
        dsp[tid * N_CAPS + c] = ev[c] * inv + pp[tid * N_CAPS + c];
    }
  };

  auto gmatvec = [&](int cc, int ii) {
    const float* Gp = Gmat + cc * 16384 + ii;
    float y0 = 0.f, y1 = 0.f;
#pragma unroll 4
    for (int j = 0; j < 128; j += 2) {
      y0 = fmaf(Gp[j * 128], dsp[j * N_CAPS + cc], y0);
      y1 = fmaf(Gp[(j + 1) * 128], dsp[(j + 1) * N_CAPS + cc], y1);
    }
    return y0 + y1;   // = hm_i . vv_raw
  };

  // ---- Gram-assisted rounds (3 barriers each) ----
  for (int r = 0; r < 2; ++r) {
    softmax_dsp();
    __syncthreads();
    float y = 0.f, sold = 0.f;
    int cc = tid >> 7, ii = tid & 127, ic = ii * N_CAPS + cc;
    if (tid < NPAIR) {
      y = gmatvec(cc, ii);
      sold = sdot[ic];
      float dmy = dsp[ic];
      float n2p = wred(dmy * y);
      float vsp = wred(dmy * ((float)D_CAPS * smm[ic]));
      float sdp = wred(dmy * sold);
      if (lane == 0) {
        red[w][0] = n2p;
        red[w][1] = vsp;
        red[w][2] = sdp;
      }
    }
    __syncthreads();
    if (tid < NPAIR) {
      float n2 = red[2 * cc][0] + red[2 * cc + 1][0];
      float vs = red[2 * cc][1] + red[2 * cc + 1][1];
      float sd = red[2 * cc][2] + red[2 * cc + 1][2];
      float sc = squash_sc(n2);
      float ts = 0.5f * (tsum_s[r & 1][cc] + sc * vs);
      float t2v = 0.25f * (t2_s[r & 1][cc] + 2.f * sc * sd + sc * sc * n2);
      if (ii == 0) {
        tsum_s[(r + 1) & 1][cc] = ts;
        t2_s[(r + 1) & 1][cc] = t2v;
      }
      float mu = ts * (1.f / D_CAPS);
      float ssqv = fmaxf(t2v - (float)D_CAPS * mu * mu, 0.f);
      float mdv = sc * y;
      aa[ic] += pp[ic] * mdv;
      float snew = 0.5f * (sold + mdv);
      sdot[ic] = snew;
      float num = snew - (float)D_CAPS * smm[ic] * mu;
      float den = sqrtf(sss[ic]) * sqrtf(ssqv) + EPSF;
      pp[ic] = tanh_fast(num / den);
    }
    __syncthreads();
  }

  // ---- final: d+p; n2 via 3rd G matvec; write dspT + scT ----
  softmax_dsp();
  __syncthreads();
  {
    int cc = tid >> 7, ii = tid & 127, ic = ii * N_CAPS + cc;
    float y = 0.f;
    if (tid < NPAIR) {
      y = gmatvec(cc, ii);
      float n2p = wred(dsp[ic] * y);
      if (lane == 0) red[w][0] = n2p;
    }
    __syncthreads();
    if (tid < NPAIR)
      dspT[(cc * NQ + qi) * 128 + ii] = dsp[ic];
    if (tid < N_CAPS) {
      float n2 = red[2 * tid][0] + red[2 * tid + 1][0];
      scT[tid * NQ + qi] = squash_sc(n2);
    }
  }
}

// ---------------------------------------------------------------------------
// Kernel 4: outgemm — out[q][c*153+d] = scT[c][q] * sum_i dspT[c][q][i] *
// hat_m[i][c*160+d].  grid (5 c, 5 dt, 8 qt), block 256.
// hm tile + dsp tile staged in LDS; hm read ~once from L2 (vs 256x before).
// ---------------------------------------------------------------------------
__global__ __launch_bounds__(256, 4)
void outgemm_kernel(const float* __restrict__ hat_m,
                    const float* __restrict__ dspT,
                    const float* __restrict__ scT,
                    const int* __restrict__ flag,
                    void* __restrict__ out_v) {
  __shared__ float hmT[128][32];     // 16 KB
  __shared__ float dspS[32][132];    // 16.5 KB (stride 132: 16B-aligned rows)

  const int c = blockIdx.x, dt = blockIdx.y, qt = blockIdx.z;
  const int tid = threadIdx.x;

  // stage hm tile: 128 i x 32 d (d0 = dt*32), float4
  for (int e = tid; e < 128 * 8; e += 256) {
    int i = e >> 3, dd4 = e & 7;
    *(float4*)&hmT[i][dd4 * 4] =
        *(const float4*)(hat_m + i * MLD + c * D_PAD + dt * 32 + dd4 * 4);
  }
  // stage dsp tile: 32 q x 128 i, float4 (contiguous source)
  for (int e = tid; e < 32 * 32; e += 256) {
    int qq = e >> 5, k4 = e & 31;
    *(float4*)&dspS[qq][k4 * 4] =
        *(const float4*)(dspT + ((long)c * NQ + qt * 32 + qq) * 128 + k4 * 4);
  }
  __syncthreads();

  const int qq = tid >> 3, dsub = tid & 7;   // 32 q x 8 d-chunks of 4
  const int q = qt * 32 + qq;
  float a0 = 0.f, a1 = 0.f, a2 = 0.f, a3 = 0.f;
#pragma unroll 2
  for (int i = 0; i < 128; ++i) {
    float dv = dspS[qq][i];
    const float4 h = *(const float4*)&hmT[i][dsub * 4];
    a0 = fmaf(dv, h.x, a0);
    a1 = fmaf(dv, h.y, a1);
    a2 = fmaf(dv, h.z, a2);
    a3 = fmaf(dv, h.w, a3);
  }
  const float sc = scT[c * NQ + q];
  const int d0 = dt * 32 + dsub * 4;
  float r[4] = {a0 * sc, a1 * sc, a2 * sc, a3 * sc};

  if (*flag == 0) {
    float* out = (float*)out_v;
#pragma unroll
    for (int k = 0; k < 4; ++k)
      if (d0 + k < D_CAPS) out[q * CD + c * D_CAPS + d0 + k] = r[k];
  } else {
    bf16* out = (bf16*)out_v;
#pragma unroll
    for (int k = 0; k < 4; ++k)
      if (d0 + k < D_CAPS)
        out[q * CD + c * D_CAPS + d0 + k] = __float2bfloat16(r[k]);
  }
}

// ---------------------------------------------------------------------------
extern "C" void kernel_launch(void* const* d_in, const int* in_sizes, int n_in,
                              void* d_out, int out_size, void* d_ws, size_t ws_size,
                              hipStream_t stream) {
  // Bind inputs by element count (order-independent).
  const void *m = nullptr, *q = nullptr, *W = nullptr, *b = nullptr;
  for (int i = 0; i < n_in; ++i) {
    switch (in_sizes[i]) {
      case I_CAPS * IN_DIM: m = d_in[i]; break;
      case NQ * IN_DIM:     q = d_in[i]; break;
      case IN_DIM * CD:     W = d_in[i]; break;
      case CD:              b = d_in[i]; break;
      default: break;
    }
  }
  if (!m || !q || !W || !b) {
    m = d_in[0]; q = d_in[1]; W = d_in[2]; b = d_in[3];
  }

  int*   flag   = (int*)d_ws;
  float* mean_m = (float*)d_ws + 16;                 // 640
  float* ssm    = mean_m + 640;                      // 640
  float* hat_m  = ssm + 640;                         // 128*800 (padded)
  float* hat_q  = hat_m + I_CAPS * MLD;              // 256*765 (packed)
  float* G      = hat_q + NQ * CD;                   // 5*128*128
  float* dspT   = G + N_CAPS * I_CAPS * I_CAPS;      // 5*256*128
  float* scT    = dspT + (size_t)N_CAPS * NQ * 128;  // 5*256

  classify_kernel<<<1, 64, 0, stream>>>((const unsigned*)m, flag);
  hipMemsetAsync(hat_m, 0,
                 ((size_t)I_CAPS * MLD + (size_t)NQ * CD) * sizeof(float),
                 stream);
  gemm_kernel<<<dim3(12, 24, 2), dim3(64, 4), 0, stream>>>(m, q, W, b, flag,
                                                           hat_m, hat_q);
  stats_kernel<<<160, 256, 0, stream>>>(hat_m, mean_m, ssm);
  gram_kernel<<<dim3(N_CAPS, I_CAPS), 128, 0, stream>>>(hat_m, G);
  routing_kernel<<<NQ, 1024, 0, stream>>>(hat_m, hat_q, G, mean_m, ssm,
                                          dspT, scT);
  outgemm_kernel<<<dim3(N_CAPS, 5, 8), 256, 0, stream>>>(hat_m, dspT, scT,
                                                         flag, d_out);
}

// Round 13
// 116.954 us; speedup vs baseline: 1.0709x; 1.0709x over previous
//
#include <hip/hip_runtime.h>
#include <hip/hip_bf16.h>

// Problem constants (fixed by the reference)
#define I_CAPS 128
#define N_CAPS 5
#define D_CAPS 153
#define D_PAD  160      // padded capsule dim (16B-aligned c-blocks, zeros in 153..159)
#define MLD    800      // hat_m leading dim = 5 * 160
#define IN_DIM 768
#define NQ     256
#define CD     765      // N_CAPS * D_CAPS
#define NPAIR  640      // I_CAPS * N_CAPS
#define EPSF   1e-8f
#define KHALF  384      // IN_DIM / 2 (split-K)

typedef __hip_bfloat16 bf16;

__device__ __forceinline__ float wred(float x) {
#pragma unroll
  for (int off = 32; off; off >>= 1) x += __shfl_down(x, off, 64);
  return x;
}

__device__ __forceinline__ float tanh_fast(float x) {
  float t = __expf(-2.f * fabsf(x));
  float r = (1.f - t) / (1.f + t);
  return copysignf(r, x);
}

// Inline dtype classifier (round-2/3 evidence: resolves to f32 here).
// bf16 inputs: low 16 bits of each m word have exponent bits in [118,134]
// (>99%); f32 inputs: ~7% hit rate. Wave-uniform result; all threads call.
__device__ __forceinline__ int is_bf16(const unsigned* __restrict__ m_u32) {
  int lane = threadIdx.x & 63;
  unsigned u = m_u32[lane];
  int e = (u >> 7) & 0xFF;
  unsigned long long mask = __ballot(e >= 118 && e <= 134);
  return __popcll(mask) >= 48;
}

// ---------------------------------------------------------------------------
// Kernel 1: GEMM — split-K x2, 8-row x 64-col tiles, atomicAdd combine.
// grid (12, 48, 2), block (64, 4). hat buffers pre-zeroed; kb==0 adds bias.
// (round-11 config — 16-row variant regressed in round 12)
// ---------------------------------------------------------------------------
template <bool ISB>
__device__ __forceinline__ float ld_in(const void* p, long idx) {
  if (ISB) return __bfloat162float(((const bf16*)p)[idx]);
  return ((const float*)p)[idx];
}

template <bool ISB>
__device__ void gemm_body(const void* m, const void* q, const void* W,
                          const void* b, float* hat_m, float* hat_q) {
  __shared__ float As[8][KHALF];   // 12 KB
  const int tx = threadIdx.x, ty = threadIdx.y;
  const int t = ty * 64 + tx;      // 0..255
  const int row0 = blockIdx.y * 8;
  const int k0 = blockIdx.z * KHALF;

  if (ISB) {
    for (int e = t; e < 8 * KHALF; e += 256) {
      int rr = e / KHALF, kk = e - rr * KHALF;
      int row = row0 + rr;
      As[rr][kk] = (row < I_CAPS)
                       ? ld_in<true>(m, (long)row * IN_DIM + k0 + kk)
                       : ld_in<true>(q, (long)(row - I_CAPS) * IN_DIM + k0 + kk);
    }
  } else {
    for (int e = t; e < 8 * (KHALF / 4); e += 256) {
      int rr = e / (KHALF / 4), k4 = e - rr * (KHALF / 4);
      int row = row0 + rr;
      const float* src = (row < I_CAPS)
                             ? (const float*)m + (long)row * IN_DIM
                             : (const float*)q + (long)(row - I_CAPS) * IN_DIM;
      *(float4*)&As[rr][k4 * 4] = *(const float4*)(src + k0 + k4 * 4);
    }
  }
  __syncthreads();

  const int col = blockIdx.x * 64 + tx;
  const int colc = (col < CD) ? col : (CD - 1);
  const int r0 = ty * 2, r1 = r0 + 1;

  float a0a = 0.f, a0b = 0.f, a1a = 0.f, a1b = 0.f;
#pragma unroll 2
  for (int k = 0; k < KHALF; k += 8) {
    const float4 A0a = *(const float4*)&As[r0][k];
    const float4 A0b = *(const float4*)&As[r0][k + 4];
    const float4 A1a = *(const float4*)&As[r1][k];
    const float4 A1b = *(const float4*)&As[r1][k + 4];
    float w0 = ld_in<ISB>(W, (long)(k0 + k + 0) * CD + colc);
    float w1 = ld_in<ISB>(W, (long)(k0 + k + 1) * CD + colc);
    float w2 = ld_in<ISB>(W, (long)(k0 + k + 2) * CD + colc);
    float w3 = ld_in<ISB>(W, (long)(k0 + k + 3) * CD + colc);
    float w4 = ld_in<ISB>(W, (long)(k0 + k + 4) * CD + colc);
    float w5 = ld_in<ISB>(W, (long)(k0 + k + 5) * CD + colc);
    float w6 = ld_in<ISB>(W, (long)(k0 + k + 6) * CD + colc);
    float w7 = ld_in<ISB>(W, (long)(k0 + k + 7) * CD + colc);
    a0a = fmaf(A0a.x, w0, a0a); a0b = fmaf(A0a.y, w1, a0b);
    a0a = fmaf(A0a.z, w2, a0a); a0b = fmaf(A0a.w, w3, a0b);
    a0a = fmaf(A0b.x, w4, a0a); a0b = fmaf(A0b.y, w5, a0b);
    a0a = fmaf(A0b.z, w6, a0a); a0b = fmaf(A0b.w, w7, a0b);
    a1a = fmaf(A1a.x, w0, a1a); a1b = fmaf(A1a.y, w1, a1b);
    a1a = fmaf(A1a.z, w2, a1a); a1b = fmaf(A1a.w, w3, a1b);
    a1a = fmaf(A1b.x, w4, a1a); a1b = fmaf(A1b.y, w5, a1b);
    a1a = fmaf(A1b.z, w6, a1a); a1b = fmaf(A1b.w, w7, a1b);
  }

  if (col < CD) {
    float p0 = a0a + a0b;
    float p1 = a1a + a1b;
    if (blockIdx.z == 0) {
      float bias = ld_in<ISB>(b, col);
      p0 += bias;
      p1 += bias;
    }
    int c = col / D_CAPS, d = col - c * D_CAPS;
    int ra = row0 + r0, rb = row0 + r1;
    float* d0 = (ra < I_CAPS) ? &hat_m[ra * MLD + c * D_PAD + d]
                              : &hat_q[(ra - I_CAPS) * CD + col];
    float* d1 = (rb < I_CAPS) ? &hat_m[rb * MLD + c * D_PAD + d]
                              : &hat_q[(rb - I_CAPS) * CD + col];
    atomicAdd(d0, p0);
    atomicAdd(d1, p1);
  }
}

__global__ __launch_bounds__(256, 4)
void gemm_kernel(const void* m, const void* q, const void* W, const void* b,
                 float* __restrict__ hat_m, float* __restrict__ hat_q) {
  if (is_bf16((const unsigned*)m))
    gemm_body<true>(m, q, W, b, hat_m, hat_q);
  else
    gemm_body<false>(m, q, W, b, hat_m, hat_q);
}

// ---------------------------------------------------------------------------
// Kernel 2: Gram matrix G[c][j][i] = hm_i,c . hm_j,c, with per-(j,c) stats
// fused on the diagonal thread (i==j: same row loads -> sum alongside dot).
// grid (5, 128), block 128.
// ---------------------------------------------------------------------------
__global__ __launch_bounds__(128)
void gram_kernel(const float* __restrict__ hat_m, float* __restrict__ G,
                 float* __restrict__ mean_m, float* __restrict__ ssm) {
  const int c = blockIdx.x, j = blockIdx.y, i = threadIdx.x;
  const float4* hi = (const float4*)(hat_m + i * MLD + c * D_PAD);
  const float4* hj = (const float4*)(hat_m + j * MLD + c * D_PAD);
  float a0 = 0.f, a1 = 0.f, a2 = 0.f, a3 = 0.f;
  float s = 0.f;
#pragma unroll 8
  for (int k = 0; k < 40; ++k) {
    float4 x = hi[k];
    float4 y = hj[k];
    a0 = fmaf(x.x, y.x, a0);
    a1 = fmaf(x.y, y.y, a1);
    a2 = fmaf(x.z, y.z, a2);
    a3 = fmaf(x.w, y.w, a3);
    s += (x.x + x.y) + (x.z + x.w);
  }
  float dot = (a0 + a1) + (a2 + a3);
  G[c * 16384 + j * 128 + i] = dot;
  if (i == j) {
    float mu = s * (1.f / D_CAPS);
    mean_m[j * N_CAPS + c] = mu;
    ssm[j * N_CAPS + c] = fmaxf(dot - (float)D_CAPS * mu * mu, 0.f);
  }
}

// ---------------------------------------------------------------------------
// Kernel 3: routing — one block per query, 1024 threads. Gram-assisted
// rounds (no hat_m traffic in rounds); init S DOT5 + final hat_v are the
// only hat_m passes. Round-11 version (round-12 outgemm split regressed).
// ---------------------------------------------------------------------------
__global__ __launch_bounds__(1024, 4)
void routing_kernel(const float* __restrict__ hat_m,
                    const float* __restrict__ hat_q,
                    const float* __restrict__ Gmat,
                    const float* __restrict__ mean_m,
                    const float* __restrict__ ssm,
                    const unsigned* __restrict__ m_u32,
                    void* __restrict__ out_v) {
  __shared__ float tq[N_CAPS * D_PAD], vv[N_CAPS * D_PAD];
  __shared__ float aa[NPAIR], pp[NPAIR], dsp[NPAIR], sdot[NPAIR];
  __shared__ float smm[NPAIR], sss[NPAIR];
  __shared__ float meanq[N_CAPS], ssq[N_CAPS], sc_s[N_CAPS];
  __shared__ float tsum_s[N_CAPS], t2_s[N_CAPS];
  __shared__ float red[10][4];

  const int tid = threadIdx.x;
  const int qi = blockIdx.x;
  const int w = tid >> 6, lane = tid & 63;
  const int g = tid >> 3, sub = tid & 7;   // 128 groups of 8 lanes; i = g
  const float* hq = hat_q + qi * CD;
  const float* hm = hat_m + g * MLD;

  for (int l = tid; l < N_CAPS * D_PAD; l += 1024) {
    int c = l / D_PAD, d = l - c * D_PAD;
    tq[l] = (d < D_CAPS) ? hq[c * D_CAPS + d] : 0.f;
  }
  if (tid < NPAIR) {
    aa[tid] = 0.f;
    smm[tid] = mean_m[tid];
    sss[tid] = ssm[tid];
  }
  __syncthreads();

  // initial per-c stats of tq; raw Tsum/T2 saved for the recurrence
  if (w < N_CAPS) {
    const int c = w;
    float s = 0.f, s2 = 0.f;
    for (int d = lane; d < D_CAPS; d += 64) {
      float x = tq[c * D_PAD + d];
      s += x;
      s2 = fmaf(x, x, s2);
    }
    s = wred(s);
    s2 = wred(s2);
    if (lane == 0) {
      float mu = s * (1.f / D_CAPS);
      tsum_s[c] = s;
      t2_s[c] = s2;
      meanq[c] = mu;
      ssq[c] = fmaxf(s2 - (float)D_CAPS * mu * mu, 0.f);
    }
  }
  __syncthreads();

  // init S = hm.tq (8-lane group per i, 5 c-chains, float4)
  {
    float A0 = 0.f, A1 = 0.f, A2 = 0.f, A3 = 0.f, A4 = 0.f;
#pragma unroll 2
    for (int jj = 0; jj < 5; ++jj) {
      int d = jj * 32 + sub * 4;
      float4 h0 = *(const float4*)(hm + 0 * D_PAD + d);
      float4 h1 = *(const float4*)(hm + 1 * D_PAD + d);
      float4 h2 = *(const float4*)(hm + 2 * D_PAD + d);
      float4 h3 = *(const float4*)(hm + 3 * D_PAD + d);
      float4 h4 = *(const float4*)(hm + 4 * D_PAD + d);
      float4 t0 = *(const float4*)(tq + 0 * D_PAD + d);
      float4 t1 = *(const float4*)(tq + 1 * D_PAD + d);
      float4 t2 = *(const float4*)(tq + 2 * D_PAD + d);
      float4 t3 = *(const float4*)(tq + 3 * D_PAD + d);
      float4 t4 = *(const float4*)(tq + 4 * D_PAD + d);
      A0 = fmaf(h0.x, t0.x, A0); A0 = fmaf(h0.y, t0.y, A0);
      A0 = fmaf(h0.z, t0.z, A0); A0 = fmaf(h0.w, t0.w, A0);
      A1 = fmaf(h1.x, t1.x, A1); A1 = fmaf(h1.y, t1.y, A1);
      A1 = fmaf(h1.z, t1.z, A1); A1 = fmaf(h1.w, t1.w, A1);
      A2 = fmaf(h2.x, t2.x, A2); A2 = fmaf(h2.y, t2.y, A2);
      A2 = fmaf(h2.z, t2.z, A2); A2 = fmaf(h2.w, t2.w, A2);
      A3 = fmaf(h3.x, t3.x, A3); A3 = fmaf(h3.y, t3.y, A3);
      A3 = fmaf(h3.z, t3.z, A3); A3 = fmaf(h3.w, t3.w, A3);
      A4 = fmaf(h4.x, t4.x, A4); A4 = fmaf(h4.y, t4.y, A4);
      A4 = fmaf(h4.z, t4.z, A4); A4 = fmaf(h4.w, t4.w, A4);
    }
#pragma unroll
    for (int off = 1; off < 8; off <<= 1) {
      A0 += __shfl_xor(A0, off, 64);
      A1 += __shfl_xor(A1, off, 64);
      A2 += __shfl_xor(A2, off, 64);
      A3 += __shfl_xor(A3, off, 64);
      A4 += __shfl_xor(A4, off, 64);
    }
    if (sub < N_CAPS) {
      float acc = A0;
      acc = (sub == 1) ? A1 : acc;
      acc = (sub == 2) ? A2 : acc;
      acc = (sub == 3) ? A3 : acc;
      acc = (sub == 4) ? A4 : acc;
      int ic = g * N_CAPS + sub;
      sdot[ic] = acc;
      float num = acc - (float)D_CAPS * smm[ic] * meanq[sub];
      float den = sqrtf(sss[ic]) * sqrtf(ssq[sub]) + EPSF;
      pp[ic] = tanh_fast(num / den);
    }
  }
  __syncthreads();

  auto softmax_dsp = [&]() {
    if (tid < I_CAPS) {
      float av[N_CAPS], ev[N_CAPS];
      float mx = -1e30f;
#pragma unroll
      for (int c = 0; c < N_CAPS; ++c) {
        av[c] = aa[tid * N_CAPS + c];
        mx = fmaxf(mx, av[c]);
      }
      float s = 0.f;
#pragma unroll
      for (int c = 0; c < N_CAPS; ++c) {
        ev[c] = __expf(av[c] - mx);
        s += ev[c];
      }
      float inv = 1.f / s;
#pragma unroll
      for (int c = 0; c < N_CAPS; ++c)
        dsp[tid * N_CAPS + c] = ev[c] * inv + pp[tid * N_CAPS + c];
    }
  };

  // ---- Gram-assisted rounds: no hat_m traffic ----
  for (int r = 0; r < 2; ++r) {
    softmax_dsp();
    __syncthreads();
    float y = 0.f, sold = 0.f;
    int cc = 0, ii = 0, ic = 0;
    if (tid < NPAIR) {
      cc = tid >> 7;              // 128 consecutive threads per c
      ii = tid & 127;
      ic = ii * N_CAPS + cc;
      const float* Gp = Gmat + cc * 16384 + ii;
      float y0 = 0.f, y1 = 0.f;
#pragma unroll 4
      for (int j = 0; j < 128; j += 2) {
        y0 = fmaf(Gp[j * 128], dsp[j * N_CAPS + cc], y0);
        y1 = fmaf(Gp[(j + 1) * 128], dsp[(j + 1) * N_CAPS + cc], y1);
      }
      y = y0 + y1;                // = hm_i . vv_raw
      sold = sdot[ic];
      float dmy = dsp[ic];
      float n2p = wred(dmy * y);
      float vsp = wred(dmy * ((float)D_CAPS * smm[ic]));
      float sdp = wred(dmy * sold);
      if (lane == 0) {
        red[w][0] = n2p;
        red[w][1] = vsp;
        red[w][2] = sdp;
      }
    }
    __syncthreads();
    if (tid < N_CAPS) {
      float n2 = red[2 * tid][0] + red[2 * tid + 1][0];
      float vs = red[2 * tid][1] + red[2 * tid + 1][1];
      float sd = red[2 * tid][2] + red[2 * tid + 1][2];
      float sc = (n2 / (1.f + n2)) * rsqrtf(n2 + EPSF);
      sc_s[tid] = sc;
      float ts = 0.5f * (tsum_s[tid] + sc * vs);
      float t2 = 0.25f * (t2_s[tid] + 2.f * sc * sd + sc * sc * n2);
      tsum_s[tid] = ts;
      t2_s[tid] = t2;
      float mu = ts * (1.f / D_CAPS);
      meanq[tid] = mu;
      ssq[tid] = fmaxf(t2 - (float)D_CAPS * mu * mu, 0.f);
    }
    __syncthreads();
    if (tid < NPAIR) {
      float mdv = sc_s[cc] * y;          // hm_i . v
      aa[ic] += pp[ic] * mdv;
      float snew = 0.5f * (sold + mdv);  // S' = 0.5(S + hm.v)
      sdot[ic] = snew;
      float num = snew - (float)D_CAPS * smm[ic] * meanq[cc];
      float den = sqrtf(sss[ic]) * sqrtf(ssq[cc]) + EPSF;
      pp[ic] = tanh_fast(num / den);
    }
    __syncthreads();
  }

  // ---- final: d+p -> hat_v (one hat_m pass) -> squash -> out ----
  softmax_dsp();
  __syncthreads();
  for (int cd = tid; cd < CD; cd += 1024) {
    int c = cd / D_CAPS, d = cd - c * D_CAPS;
    const float* col = hat_m + c * D_PAD + d;
    float b0 = 0.f, b1 = 0.f, b2 = 0.f, b3 = 0.f;
    float b4 = 0.f, b5 = 0.f, b6 = 0.f, b7 = 0.f;
#pragma unroll 4
    for (int i = 0; i < I_CAPS; i += 8) {
      b0 = fmaf(dsp[(i + 0) * N_CAPS + c], col[(i + 0) * MLD], b0);
      b1 = fmaf(dsp[(i + 1) * N_CAPS + c], col[(i + 1) * MLD], b1);
      b2 = fmaf(dsp[(i + 2) * N_CAPS + c], col[(i + 2) * MLD], b2);
      b3 = fmaf(dsp[(i + 3) * N_CAPS + c], col[(i + 3) * MLD], b3);
      b4 = fmaf(dsp[(i + 4) * N_CAPS + c], col[(i + 4) * MLD], b4);
      b5 = fmaf(dsp[(i + 5) * N_CAPS + c], col[(i + 5) * MLD], b5);
      b6 = fmaf(dsp[(i + 6) * N_CAPS + c], col[(i + 6) * MLD], b6);
      b7 = fmaf(dsp[(i + 7) * N_CAPS + c], col[(i + 7) * MLD], b7);
    }
    vv[c * D_PAD + d] = ((b0 + b1) + (b2 + b3)) + ((b4 + b5) + (b6 + b7));
  }
  __syncthreads();
  if (w < N_CAPS) {
    const int c = w;
    float s2 = 0.f;
    for (int d = lane; d < D_CAPS; d += 64) {
      float x = vv[c * D_PAD + d];
      s2 = fmaf(x, x, s2);
    }
    s2 = wred(s2);
    if (lane == 0) sc_s[c] = (s2 / (1.f + s2)) * rsqrtf(s2 + EPSF);
  }
  __syncthreads();

  int isb = is_bf16(m_u32);   // all threads call (wave-uniform ballot)
  if (!isb) {
    float* out = (float*)out_v;
    for (int cd = tid; cd < CD; cd += 1024) {
      int c = cd / D_CAPS, d = cd - c * D_CAPS;
      out[qi * CD + cd] = vv[c * D_PAD + d] * sc_s[c];
    }
  } else {
    bf16* out = (bf16*)out_v;
    for (int cd = tid; cd < CD; cd += 1024) {
      int c = cd / D_CAPS, d = cd - c * D_CAPS;
      out[qi * CD + cd] = __float2bfloat16(vv[c * D_PAD + d] * sc_s[c]);
    }
  }
}

// ---------------------------------------------------------------------------
extern "C" void kernel_launch(void* const* d_in, const int* in_sizes, int n_in,
                              void* d_out, int out_size, void* d_ws, size_t ws_size,
                              hipStream_t stream) {
  // Bind inputs by element count (order-independent):
  // m=98304, q=196608, W=587520, b=765.
  const void *m = nullptr, *q = nullptr, *W = nullptr, *b = nullptr;
  for (int i = 0; i < n_in; ++i) {
    switch (in_sizes[i]) {
      case I_CAPS * IN_DIM: m = d_in[i]; break;
      case NQ * IN_DIM:     q = d_in[i]; break;
      case IN_DIM * CD:     W = d_in[i]; break;
      case CD:              b = d_in[i]; break;
      default: break;
    }
  }
  if (!m || !q || !W || !b) {
    m = d_in[0]; q = d_in[1]; W = d_in[2]; b = d_in[3];
  }

  float* mean_m = (float*)d_ws + 16;                 // 640
  float* ssm    = mean_m + 640;                      // 640
  float* hat_m  = ssm + 640;                         // 128*800 (padded)
  float* hat_q  = hat_m + I_CAPS * MLD;              // 256*765 (packed)
  float* G      = hat_q + NQ * CD;                   // 5*128*128

  // zero hat_m (incl. pads) + hat_q (split-K atomics accumulate into these)
  hipMemsetAsync(hat_m, 0,
                 ((size_t)I_CAPS * MLD + (size_t)NQ * CD) * sizeof(float),
                 stream);
  gemm_kernel<<<dim3(12, 48, 2), dim3(64, 4), 0, stream>>>(m, q, W, b,
                                                           hat_m, hat_q);
  gram_kernel<<<dim3(N_CAPS, I_CAPS), 128, 0, stream>>>(hat_m, G,
                                                        mean_m, ssm);
  routing_kernel<<<NQ, 1024, 0, stream>>>(hat_m, hat_q, G, mean_m, ssm,
                                          (const unsigned*)m, d_out);
}